// Round 1
// 274.345 us; speedup vs baseline: 1.0204x; 1.0204x over previous
//
#include <hip/hip_runtime.h>

typedef unsigned short bhalf;
typedef __bf16 bf16x8 __attribute__((ext_vector_type(8)));
typedef float f32x4 __attribute__((ext_vector_type(4)));

#define NQ 4096
#define NK 32768
#define DIN 1024
#define DQK 512
#define CAP 64  // keyslot capacity per query (mean 8, binomial tail @64 ~ 0)
#define SCALE 0.044194173824159216f  // 1/sqrt(512)

__device__ __forceinline__ unsigned f2bf(float f) {
  union { float f; unsigned u; } c; c.f = f;
  unsigned u = c.u;
  return (u + 0x7fffu + ((u >> 16) & 1u)) >> 16;  // RNE
}
__device__ __forceinline__ float bf_lo(unsigned u) {
  union { unsigned u; float f; } c; c.u = u << 16; return c.f;
}
__device__ __forceinline__ float bf_hi(unsigned u) {
  union { unsigned u; float f; } c; c.u = u & 0xffff0000u; return c.f;
}

// ---- fused prep: transpose Wv, g vector, cvt Wq/Wk/X1, fused hist+scatter ----
// Query-constant softmax bias terms cancel; only g = scale*(Wk@bq) survives.
// ranges: [0,512) transposeWv | [512,768) g | [768,1280) cvtWq |
//         [1280,1792) cvtWk | [1792,1920) hist+scatter | [1920,6016) cvtX1
__global__ __launch_bounds__(256) void prep_kernel(
    const float* __restrict__ Wq, const float* __restrict__ Wk,
    const float* __restrict__ Wv, const float* __restrict__ bq,
    const float* __restrict__ X1, const int* __restrict__ rm,
    bhalf* __restrict__ Wq_b, bhalf* __restrict__ Wk_b, bhalf* __restrict__ WvT,
    bhalf* __restrict__ X1_b,
    float* __restrict__ g_s, int* __restrict__ cnt, int* __restrict__ keyslot) {
  __shared__ float tile[32][33];
  const int b = blockIdx.x;
  const int tid = threadIdx.x;
  if (b < 512) {
    const int bx = b & 15, by = b >> 4;
    const int tx = tid & 31, ty = tid >> 5;
    const int x = bx * 32 + tx;
#pragma unroll
    for (int yy = 0; yy < 32; yy += 8)
      tile[ty + yy][tx] = Wv[(size_t)(by * 32 + ty + yy) * 512 + x];
    __syncthreads();
    const int k = by * 32 + tx;
#pragma unroll
    for (int yy = 0; yy < 32; yy += 8)
      WvT[(size_t)(bx * 32 + ty + yy) * 1024 + k] = (bhalf)f2bf(tile[tx][ty + yy]);
  } else if (b < 768) {
    const int w = (b - 512) * 4 + (tid >> 6);  // 0..1023
    const int lane = tid & 63;
    const float* row = Wk + (size_t)w * 512;
    float s = 0.f;
#pragma unroll
    for (int t = 0; t < 2; t++) {
      float4 a = *(const float4*)(row + t * 256 + lane * 4);
      float4 bb2 = *(const float4*)(bq + t * 256 + lane * 4);
      s += a.x * bb2.x + a.y * bb2.y + a.z * bb2.z + a.w * bb2.w;
    }
#pragma unroll
    for (int d = 32; d; d >>= 1) s += __shfl_xor(s, d);
    if (lane == 0) g_s[w] = s * SCALE;
  } else if (b < 1792) {
    const float* in; bhalf* out; int idx;
    if (b < 1280) { in = Wq; out = Wq_b; idx = (b - 768) * 256 + tid; }
    else          { in = Wk; out = Wk_b; idx = (b - 1280) * 256 + tid; }
    float4 v = ((const float4*)in)[idx];
    uint2 o;
    o.x = f2bf(v.x) | (f2bf(v.y) << 16);
    o.y = f2bf(v.z) | (f2bf(v.w) << 16);
    ((uint2*)out)[idx] = o;
  } else if (b < 1920) {
    const int j = (b - 1792) * 256 + tid;
    const int i = rm[j];
    const int p = atomicAdd(&cnt[i], 1);
    if (p < CAP) keyslot[(size_t)i * CAP + p] = j;
  } else {
    // cvt X1 (4096x1024 fp32 -> bf16), once, instead of 8x in-GEMM re-conversion
    const int idx = (b - 1920) * 256 + tid;
    float4 v = ((const float4*)X1)[idx];
    uint2 o;
    o.x = f2bf(v.x) | (f2bf(v.y) << 16);
    o.y = f2bf(v.z) | (f2bf(v.w) << 16);
    ((uint2*)X1_b)[idx] = o;
  }
}

// ---- GEMM core: C(MxN) = A(MxK) @ Bt(NxK,bf16)^T, (MI*32)x128 tile, BK=64 ----
// AF32=1 (requires MI=2): A is fp32, converted to bf16 during LDS staging.
// MODE 0: bf16 out, acc*SCALE | MODE 1: bf16 out, acc+bias | MODE 2: fp32 out, +bias, zero empty rows
template <int MODE, int MI, int AF32>
__global__ __launch_bounds__(256) void gemm_core(
    const bhalf* __restrict__ A, const float* __restrict__ Afp,
    const bhalf* __restrict__ Bt,
    const float* __restrict__ bias, const int* __restrict__ cnt,
    void* __restrict__ Cout, int M, int N, int K, int nnt) {
  __shared__ __align__(16) bhalf As[MI * 32 * 64];
  __shared__ __align__(16) bhalf Bs[128 * 64];
  const int bid = blockIdx.x;
  const int mt = bid / nnt, nt = bid % nnt;
  const int bmb = mt * (MI * 32), bnb = nt * 128;

  const int tid = threadIdx.x;
  const int lane = tid & 63;
  const int wv = tid >> 6;
  const int wm = (wv & 1) * (MI * 16);
  const int wn = (wv >> 1) * 64;
  const int quad = lane >> 4;
  const int l15 = lane & 15;

  f32x4 acc[MI][4];
#pragma unroll
  for (int i = 0; i < MI; i++)
#pragma unroll
    for (int j = 0; j < 4; j++)
#pragma unroll
      for (int r = 0; r < 4; r++) acc[i][j][r] = 0.0f;

  const int srow = lane >> 3;
  const int scol = (lane & 7) ^ srow;  // XOR swizzle applied on global side

  for (int kb = 0; kb < K; kb += 64) {
    const size_t goff = (size_t)kb + (size_t)scol * 8;
    if (AF32) {
      // 64x64 fp32 tile: thread -> row R=tid>>2, 16 cols at q4*16; cvt; swizzled b128 writes
      const int R = tid >> 2;
      const int q4 = tid & 3;
      const float* arow = Afp + (size_t)(bmb + R) * K + kb + q4 * 16;
      float4 v0 = *(const float4*)(arow + 0);
      float4 v1 = *(const float4*)(arow + 4);
      float4 v2 = *(const float4*)(arow + 8);
      float4 v3 = *(const float4*)(arow + 12);
      uint4 o0, o1;
      o0.x = f2bf(v0.x) | (f2bf(v0.y) << 16);
      o0.y = f2bf(v0.z) | (f2bf(v0.w) << 16);
      o0.z = f2bf(v1.x) | (f2bf(v1.y) << 16);
      o0.w = f2bf(v1.z) | (f2bf(v1.w) << 16);
      o1.x = f2bf(v2.x) | (f2bf(v2.y) << 16);
      o1.y = f2bf(v2.z) | (f2bf(v2.w) << 16);
      o1.z = f2bf(v3.x) | (f2bf(v3.y) << 16);
      o1.w = f2bf(v3.z) | (f2bf(v3.w) << 16);
      const int u0 = q4 * 2, u1 = q4 * 2 + 1;
      *(uint4*)(As + R * 64 + (u0 ^ (R & 7)) * 8) = o0;
      *(uint4*)(As + R * 64 + (u1 ^ (R & 7)) * 8) = o1;
    } else {
#pragma unroll
      for (int r = 0; r < MI; r++) {
        const int chunk = wv * MI + r;
        const int row = chunk * 8 + srow;
        __builtin_amdgcn_global_load_lds(
            (__attribute__((address_space(1))) unsigned int*)(A + (size_t)(bmb + row) * K + goff),
            (__attribute__((address_space(3))) unsigned int*)(As + chunk * 512), 16, 0, 0);
      }
    }
#pragma unroll
    for (int r = 0; r < 4; r++) {
      const int chunk = wv * 4 + r;
      const int row = chunk * 8 + srow;
      __builtin_amdgcn_global_load_lds(
          (__attribute__((address_space(1))) unsigned int*)(Bt + (size_t)(bnb + row) * K + goff),
          (__attribute__((address_space(3))) unsigned int*)(Bs + chunk * 512), 16, 0, 0);
    }
    __syncthreads();
#pragma unroll
    for (int ks = 0; ks < 2; ks++) {
      const int su = ((ks * 4 + quad) ^ (lane & 7)) * 8;
      bf16x8 af[MI], bfr[4];
#pragma unroll
      for (int i = 0; i < MI; i++)
        af[i] = *(const bf16x8*)(As + (wm + i * 16 + l15) * 64 + su);
#pragma unroll
      for (int j = 0; j < 4; j++)
        bfr[j] = *(const bf16x8*)(Bs + (wn + j * 16 + l15) * 64 + su);
#pragma unroll
      for (int i = 0; i < MI; i++)
#pragma unroll
        for (int j = 0; j < 4; j++)
          acc[i][j] = __builtin_amdgcn_mfma_f32_16x16x32_bf16(af[i], bfr[j], acc[i][j], 0, 0, 0);
    }
    __syncthreads();
  }
#pragma unroll
  for (int j = 0; j < 4; j++) {
    const int col = bnb + wn + j * 16 + l15;
    const float bs = (MODE >= 1) ? bias[col] : 0.0f;
#pragma unroll
    for (int i = 0; i < MI; i++) {
#pragma unroll
      for (int r = 0; r < 4; r++) {
        const int row = bmb + wm + i * 16 + quad * 4 + r;
        const float v = acc[i][j][r];
        if (MODE == 0) {
          ((bhalf*)Cout)[(size_t)row * N + col] = (bhalf)f2bf(v * SCALE);
        } else if (MODE == 1) {
          ((bhalf*)Cout)[(size_t)row * N + col] = (bhalf)f2bf(v + bs);
        } else {
          ((float*)Cout)[(size_t)row * N + col] = (cnt[row] > 0) ? (v + bs) : 0.0f;
        }
      }
    }
  }
}

// ---- fused score + weighted X2 sum, single pass, 2-way j-unroll for MLP ----
// s_j = X2_j . P'_i ; w = exp(s); U_i = sum w_j X2_j / sum w_j.
__global__ __launch_bounds__(256) void scorewsum_kernel(
    const bhalf* __restrict__ P, const float* __restrict__ X2,
    const int* __restrict__ cnt, const int* __restrict__ keyslot,
    bhalf* __restrict__ Ub) {
  const int wv = threadIdx.x >> 6;
  const int i = blockIdx.x * 4 + wv;
  const int lane = threadIdx.x & 63;
  int c = cnt[i];
  if (c > CAP) c = CAP;
  const int* klist = keyslot + (size_t)i * CAP;
  const bhalf* Prow = P + (size_t)i * 1024;
  uint4 pb[2];
#pragma unroll
  for (int t = 0; t < 2; t++) pb[t] = *(const uint4*)(Prow + t * 512 + lane * 8);
  float pf[16];
#pragma unroll
  for (int t = 0; t < 2; t++) {
    pf[t * 8 + 0] = bf_lo(pb[t].x); pf[t * 8 + 1] = bf_hi(pb[t].x);
    pf[t * 8 + 2] = bf_lo(pb[t].y); pf[t * 8 + 3] = bf_hi(pb[t].y);
    pf[t * 8 + 4] = bf_lo(pb[t].z); pf[t * 8 + 5] = bf_hi(pb[t].z);
    pf[t * 8 + 6] = bf_lo(pb[t].w); pf[t * 8 + 7] = bf_hi(pb[t].w);
  }

  float sumw = 0.f;
  float4 u[4] = {};
  int pp = 0;
  for (; pp + 2 <= c; pp += 2) {
    const int j0 = klist[pp];
    const int j1 = klist[pp + 1];
    const float* xr0 = X2 + (size_t)j0 * 1024;
    const float* xr1 = X2 + (size_t)j1 * 1024;
    float4 x0[4], x1[4];
#pragma unroll
    for (int t = 0; t < 2; t++) {
      x0[t * 2]     = *(const float4*)(xr0 + t * 512 + lane * 8);
      x0[t * 2 + 1] = *(const float4*)(xr0 + t * 512 + lane * 8 + 4);
      x1[t * 2]     = *(const float4*)(xr1 + t * 512 + lane * 8);
      x1[t * 2 + 1] = *(const float4*)(xr1 + t * 512 + lane * 8 + 4);
    }
    float s0 = 0.f, s1 = 0.f;
#pragma unroll
    for (int t = 0; t < 4; t++) {
      s0 += pf[t * 4 + 0] * x0[t].x + pf[t * 4 + 1] * x0[t].y
          + pf[t * 4 + 2] * x0[t].z + pf[t * 4 + 3] * x0[t].w;
      s1 += pf[t * 4 + 0] * x1[t].x + pf[t * 4 + 1] * x1[t].y
          + pf[t * 4 + 2] * x1[t].z + pf[t * 4 + 3] * x1[t].w;
    }
#pragma unroll
    for (int d = 32; d; d >>= 1) {
      s0 += __shfl_xor(s0, d);
      s1 += __shfl_xor(s1, d);
    }
    const float w0 = __expf(s0);
    const float w1 = __expf(s1);
    sumw += w0 + w1;
#pragma unroll
    for (int t = 0; t < 4; t++) {
      u[t].x += w0 * x0[t].x + w1 * x1[t].x;
      u[t].y += w0 * x0[t].y + w1 * x1[t].y;
      u[t].z += w0 * x0[t].z + w1 * x1[t].z;
      u[t].w += w0 * x0[t].w + w1 * x1[t].w;
    }
  }
  if (pp < c) {
    const int j = klist[pp];
    const float* xr = X2 + (size_t)j * 1024;
    float4 x[4];
#pragma unroll
    for (int t = 0; t < 2; t++) {
      x[t * 2]     = *(const float4*)(xr + t * 512 + lane * 8);
      x[t * 2 + 1] = *(const float4*)(xr + t * 512 + lane * 8 + 4);
    }
    float s = 0.f;
#pragma unroll
    for (int t = 0; t < 4; t++)
      s += pf[t * 4 + 0] * x[t].x + pf[t * 4 + 1] * x[t].y
         + pf[t * 4 + 2] * x[t].z + pf[t * 4 + 3] * x[t].w;
#pragma unroll
    for (int d = 32; d; d >>= 1) s += __shfl_xor(s, d);
    const float w = __expf(s);
    sumw += w;
#pragma unroll
    for (int t = 0; t < 4; t++) {
      u[t].x += w * x[t].x; u[t].y += w * x[t].y;
      u[t].z += w * x[t].z; u[t].w += w * x[t].w;
    }
  }
  const float inv = (c > 0) ? 1.f / sumw : 0.f;  // empty queries -> zero rows
  bhalf* urow = Ub + (size_t)i * 1024;
#pragma unroll
  for (int t = 0; t < 2; t++) {
    uint4 o;
    o.x = f2bf(u[t * 2].x * inv) | (f2bf(u[t * 2].y * inv) << 16);
    o.y = f2bf(u[t * 2].z * inv) | (f2bf(u[t * 2].w * inv) << 16);
    o.z = f2bf(u[t * 2 + 1].x * inv) | (f2bf(u[t * 2 + 1].y * inv) << 16);
    o.w = f2bf(u[t * 2 + 1].z * inv) | (f2bf(u[t * 2 + 1].w * inv) << 16);
    *(uint4*)(urow + t * 512 + lane * 8) = o;
  }
}

extern "C" void kernel_launch(void* const* d_in, const int* in_sizes, int n_in,
                              void* d_out, int out_size, void* d_ws, size_t ws_size,
                              hipStream_t stream) {
  const float* X1 = (const float*)d_in[0];
  const float* X2 = (const float*)d_in[1];
  const float* Wq = (const float*)d_in[2];
  const float* bq = (const float*)d_in[3];
  const float* Wk = (const float*)d_in[4];
  const float* Wv = (const float*)d_in[6];
  const float* bv = (const float*)d_in[7];
  const int* row_map = (const int*)d_in[8];
  float* out = (float*)d_out;

  char* p = (char*)d_ws;
  bhalf* Wq_b = (bhalf*)p; p += (size_t)DIN * DQK * 2;     // 1 MiB
  bhalf* Wk_b = (bhalf*)p; p += (size_t)DIN * DQK * 2;     // 1 MiB
  bhalf* WvT  = (bhalf*)p; p += (size_t)DQK * DIN * 2;     // 1 MiB
  bhalf* Bt2  = (bhalf*)p; p += (size_t)DIN * DIN * 2;     // 2 MiB (scaled Wqk^T)
  bhalf* X1_b = (bhalf*)p; p += (size_t)NQ * DIN * 2;      // 8 MiB (bf16 X1)
  bhalf* Pbuf = (bhalf*)p; p += (size_t)NQ * DIN * 2;      // 8 MiB (bf16 P')
  bhalf* Ub   = (bhalf*)p; p += (size_t)NQ * DIN * 2;      // 8 MiB
  float* g_s  = (float*)p; p += DIN * 4;
  int* cnt    = (int*)p;   p += NQ * 4;
  int* keyslot = (int*)p;  p += (size_t)NQ * CAP * 4;      // 1 MiB

  hipMemsetAsync(cnt, 0, (size_t)NQ * 4, stream);

  // 1920 mixed-prep blocks + 4096 X1-cvt blocks
  prep_kernel<<<6016, 256, 0, stream>>>(Wq, Wk, Wv, bq, X1, row_map,
                                        Wq_b, Wk_b, WvT, X1_b, g_s, cnt, keyslot);

  // Bt2[n,k] = scale * sum_r Wk[n,r]*Wq[k,r]   (MI=1: 32x128 tiles, 256 blocks)
  gemm_core<0, 1, 0><<<256, 256, 0, stream>>>(Wk_b, nullptr, Wq_b, nullptr, nullptr,
                                              Bt2, 1024, 1024, 512, 8);
  // P'[i,n] = sum_k X1[i,k]*Bt2[n,k] + g_s[n]  (MI=2, pre-converted bf16 A,
  // global_load_lds staging path -- no per-n-tile fp32->bf16 re-conversion)
  gemm_core<1, 2, 0><<<512, 256, 0, stream>>>(X1_b, nullptr, Bt2, g_s, nullptr,
                                              Pbuf, 4096, 1024, 1024, 8);

  scorewsum_kernel<<<NQ / 4, 256, 0, stream>>>(Pbuf, X2, cnt, keyslot, Ub);

  // out[i,col] = sum_k Ub[i,k]*WvT[col,k] + bv[col], zero for empty queries
  gemm_core<2, 2, 0><<<256, 256, 0, stream>>>(Ub, nullptr, WvT, bv, cnt,
                                              out, 4096, 512, 1024, 4);
}